// Round 5
// baseline (179.614 us; speedup 1.0000x reference)
//
#include <hip/hip_runtime.h>

// GCN aggregation: out[t] = norm[t] * sum_{e:dst=t} norm[src]*x[src] + EPS*x[t]
// Round 14: per-block-region partition. Previous partition scattered 4B stores
// into a globally shared rec[] -> fragment-boundary cache lines co-written by
// blocks on different XCDs (RFO fetch + multi-writeback + coherence stalls) +
// 60K device-scope reserve atomics; it ran at ~2% VALU / ~10% occupancy. Now
// each block LDS-sorts its 4096 edges by dst-bucket (and src-bucket) and
// streams them uint4-coalesced to its OWN region recB[blk][0..EPB), plus u16
// prefix tables tabD/tabS[blk][b]. Readers locate bucket b's records as NBLK
// segments via the tables (scattered READS are cheap: no RFO, L3-served).
// Deleted: init memset, curD/curS atomics, all overflow paths, cleanup launch.
// 3 launches total: partition, normyh, sortgather. Sortgather has a chunked
// rare path for buckets with >CAPB records (correct for any distribution).
constexpr int D        = 64;
constexpr float EPS    = 0.5f;
constexpr int BKT      = 256;    // nodes per bucket
constexpr int CAPB     = 6144;   // sortgather LDS chunk capacity (records)
constexpr int EPB      = 4096;   // edges per partition block (= region stride)
constexpr int PTHREADS = 512;
constexpr int EPT      = EPB / PTHREADS;   // 8
constexpr int GTHREADS = 1024;
constexpr int NBMAX    = 1024;   // max node buckets
constexpr int MAXBLK   = 1024;   // max partition blocks

__device__ __forceinline__ unsigned int f2bf(float f) {
    unsigned int u = __float_as_uint(f);
    return (u + 0x7FFFu + ((u >> 16) & 1u)) >> 16;   // RNE to bf16
}
__device__ __forceinline__ float bf2f_lo(unsigned int v) { return __uint_as_float(v << 16); }
__device__ __forceinline__ float bf2f_hi(unsigned int v) { return __uint_as_float(v & 0xFFFF0000u); }

// ---------------- main path ----------------

// Each block owns edges [blk*EPB, blk*EPB+cnt) and its own output region.
// Writes: recB[blk][i] (u32, sorted by dst-bucket), srecB[blk][i] (u8, sorted
// by src-bucket), tabD/tabS[blk][0..NB] = exclusive scan (u16). All streaming.
__global__ __launch_bounds__(PTHREADS)
void partition_kernel(const int* __restrict__ src, const int* __restrict__ dst,
                      unsigned int* __restrict__ recB, unsigned char* __restrict__ srecB,
                      unsigned short* __restrict__ tabD, unsigned short* __restrict__ tabS,
                      int E, int NB, int NBP) {
    __shared__ unsigned int  srt[EPB];      // 16 KB sorted dst-records
    __shared__ unsigned char ssrt[EPB];     // 4 KB sorted src bytes
    __shared__ int histD[NBMAX];            // count, then rank
    __shared__ int histS[NBMAX];
    __shared__ unsigned int rsD[NBMAX];     // exclusive scan
    __shared__ unsigned int rsS[NBMAX];
    __shared__ unsigned int wsums[PTHREADS / 64];
    __shared__ unsigned int carry;

    const int blk  = blockIdx.x;
    const int base = blk * EPB;
    const int tid  = threadIdx.x;
    const int lane = tid & 63;
    const int wid  = tid >> 6;
    const int cnt  = min(EPB, E - base);
    const bool full = (cnt == EPB);

    for (int b = tid; b < NB; b += PTHREADS) { histD[b] = 0; histS[b] = 0; }
    __syncthreads();

    // ---- pass 1: count per bucket ----
    if (full) {
        const int4* s4 = (const int4*)(src + base);
        const int4* d4 = (const int4*)(dst + base);
        #pragma unroll
        for (int k = 0; k < EPT / 4; ++k) {
            int4 sv = s4[tid + k * PTHREADS];
            int4 dv = d4[tid + k * PTHREADS];
            atomicAdd(&histD[dv.x >> 8], 1); atomicAdd(&histS[sv.x >> 8], 1);
            atomicAdd(&histD[dv.y >> 8], 1); atomicAdd(&histS[sv.y >> 8], 1);
            atomicAdd(&histD[dv.z >> 8], 1); atomicAdd(&histS[sv.z >> 8], 1);
            atomicAdd(&histD[dv.w >> 8], 1); atomicAdd(&histS[sv.w >> 8], 1);
        }
    } else {
        for (int k = 0; k < EPT; ++k) {
            int e = tid + k * PTHREADS;
            if (e < cnt) {
                atomicAdd(&histD[dst[base + e] >> 8], 1);
                atomicAdd(&histS[src[base + e] >> 8], 1);
            }
        }
    }
    __syncthreads();

    // ---- exclusive scan histD->rsD (zeroing histD for rank reuse) ----
    if (tid == 0) carry = 0;
    __syncthreads();
    for (int bp = 0; bp < NB; bp += PTHREADS) {
        int idx = bp + tid;
        unsigned int orig = (idx < NB) ? (unsigned int)histD[idx] : 0u;
        if (idx < NB) histD[idx] = 0;
        unsigned int v = orig;
        #pragma unroll
        for (int off = 1; off < 64; off <<= 1) {
            unsigned int t = __shfl_up(v, off);
            if (lane >= off) v += t;
        }
        if (lane == 63) wsums[wid] = v;
        __syncthreads();
        unsigned int add = carry;
        for (int w = 0; w < wid; ++w) add += wsums[w];
        if (idx < NB) rsD[idx] = v - orig + add;
        __syncthreads();
        if (tid == 0) {
            unsigned int s = carry;
            for (int w = 0; w < PTHREADS / 64; ++w) s += wsums[w];
            carry = s;
        }
        __syncthreads();
    }
    // ---- exclusive scan histS->rsS ----
    if (tid == 0) carry = 0;
    __syncthreads();
    for (int bp = 0; bp < NB; bp += PTHREADS) {
        int idx = bp + tid;
        unsigned int orig = (idx < NB) ? (unsigned int)histS[idx] : 0u;
        if (idx < NB) histS[idx] = 0;
        unsigned int v = orig;
        #pragma unroll
        for (int off = 1; off < 64; off <<= 1) {
            unsigned int t = __shfl_up(v, off);
            if (lane >= off) v += t;
        }
        if (lane == 63) wsums[wid] = v;
        __syncthreads();
        unsigned int add = carry;
        for (int w = 0; w < wid; ++w) add += wsums[w];
        if (idx < NB) rsS[idx] = v - orig + add;
        __syncthreads();
        if (tid == 0) {
            unsigned int s = carry;
            for (int w = 0; w < PTHREADS / 64; ++w) s += wsums[w];
            carry = s;
        }
        __syncthreads();
    }

    // ---- write prefix tables (coalesced u16) ----
    for (int b = tid; b <= NB; b += PTHREADS) {
        unsigned short vD = (unsigned short)((b < NB) ? rsD[b] : (unsigned int)cnt);
        unsigned short vS = (unsigned short)((b < NB) ? rsS[b] : (unsigned int)cnt);
        tabD[(size_t)blk * NBP + b] = vD;
        tabS[(size_t)blk * NBP + b] = vS;
    }

    // ---- pass 2: place into LDS sorted position ----
    if (full) {
        const int4* s4 = (const int4*)(src + base);
        const int4* d4 = (const int4*)(dst + base);
        #pragma unroll
        for (int k = 0; k < EPT / 4; ++k) {
            int4 sv = s4[tid + k * PTHREADS];
            int4 dv = d4[tid + k * PTHREADS];
            int ss[4] = {sv.x, sv.y, sv.z, sv.w};
            int tt[4] = {dv.x, dv.y, dv.z, dv.w};
            #pragma unroll
            for (int j = 0; j < 4; ++j) {
                int s = ss[j], t = tt[j];
                int bD = t >> 8;
                int r  = atomicAdd(&histD[bD], 1);
                srt[rsD[bD] + r] = ((unsigned int)s << 8) | (unsigned int)(t & (BKT - 1));
                int bS = s >> 8;
                int r2 = atomicAdd(&histS[bS], 1);
                ssrt[rsS[bS] + r2] = (unsigned char)(s & (BKT - 1));
            }
        }
    } else {
        for (int k = 0; k < EPT; ++k) {
            int e = tid + k * PTHREADS;
            if (e < cnt) {
                int s = src[base + e], t = dst[base + e];
                int bD = t >> 8;
                int r  = atomicAdd(&histD[bD], 1);
                srt[rsD[bD] + r] = ((unsigned int)s << 8) | (unsigned int)(t & (BKT - 1));
                int bS = s >> 8;
                int r2 = atomicAdd(&histS[bS], 1);
                ssrt[rsS[bS] + r2] = (unsigned char)(s & (BKT - 1));
            }
        }
    }
    __syncthreads();

    // ---- pass 3: stream full region out (bytes beyond cnt are never read) ----
    {
        uint4* go = (uint4*)(recB + (size_t)blk * EPB);
        const uint4* gi = (const uint4*)srt;
        for (int i = tid; i < EPB / 4; i += PTHREADS) go[i] = gi[i];
        uint4* so = (uint4*)(srecB + (size_t)blk * EPB);
        const uint4* si = (const uint4*)ssrt;
        for (int i = tid; i < EPB / 16; i += PTHREADS) so[i] = si[i];
    }
}

// Per-bucket: out-degree histogram from srecB segments -> norm[] -> yh.
__global__ __launch_bounds__(256)
void normyh_kernel(const unsigned char* __restrict__ srecB, const unsigned short* __restrict__ tabS,
                   const float2* __restrict__ x2, unsigned int* __restrict__ yh,
                   float* __restrict__ norm, int n, int NBLK, int NBP) {
    const int b   = blockIdx.x;
    const int tid = threadIdx.x;
    __shared__ int hist[BKT];
    __shared__ float nrm[BKT];
    hist[tid] = 0;                             // BKT == blockDim == 256
    __syncthreads();
    for (int blk = tid; blk < NBLK; blk += 256) {
        int o0 = tabS[(size_t)blk * NBP + b];
        int o1 = tabS[(size_t)blk * NBP + b + 1];
        const unsigned char* p = srecB + (size_t)blk * EPB;
        for (int j = o0; j < o1; ++j) atomicAdd(&hist[p[j]], 1);
    }
    __syncthreads();
    int node = b * BKT + tid;
    float nm = rsqrtf(fmaxf((float)hist[tid], 1.0f));
    nrm[tid] = nm;
    if (node < n) norm[node] = nm;
    __syncthreads();
    int nodes = n - b * BKT;
    if (nodes > BKT) nodes = BKT;
    if (nodes < 0) nodes = 0;
    int total = nodes * (D / 2);               // float2 elements in this bucket
    size_t gbase = (size_t)b * BKT * (D / 2);
    for (int i = tid; i < total; i += 256) {   // contiguous -> coalesced
        float2 v = x2[gbase + i];
        float nm2 = nrm[i >> 5];
        yh[gbase + i] = f2bf(v.x * nm2) | (f2bf(v.y * nm2) << 16);
    }
}

// One block per bucket (1024 threads = 16 waves). Gather bucket b's records
// from NBLK per-block segments into LDS, counting-sort to per-node src lists,
// then gather yh rows (8 nodes/wave, 8-deep unroll). Chunked if cnt > CAPB.
__global__ __launch_bounds__(GTHREADS)
void sortgather_kernel(const unsigned int* __restrict__ recB, const unsigned short* __restrict__ tabD,
                       const float* __restrict__ norm, const uint4* __restrict__ yr4,
                       const float4* __restrict__ x4, float4* __restrict__ out4,
                       int n, int NBLK, int NBP) {
    __shared__ unsigned int recs[CAPB];        // 24 KB
    __shared__ unsigned int srcs[CAPB];        // 24 KB
    __shared__ unsigned short segoff[MAXBLK];  // 2 KB
    __shared__ unsigned int dstoff[MAXBLK + 1];// 4 KB (len -> exclusive scan)
    __shared__ int hist[BKT];
    __shared__ int rankb[BKT];
    __shared__ int rsL[BKT];
    __shared__ float nrmL[BKT];
    __shared__ unsigned int wsums[GTHREADS / 64];
    __shared__ unsigned int carry;
    const int b    = blockIdx.x;
    const int tid  = threadIdx.x;
    const int lane = tid & 63;
    const int wid  = tid >> 6;

    // segment table for this bucket
    for (int blk = tid; blk < NBLK; blk += GTHREADS) {
        unsigned int o0 = tabD[(size_t)blk * NBP + b];
        unsigned int o1 = tabD[(size_t)blk * NBP + b + 1];
        segoff[blk] = (unsigned short)o0;
        dstoff[blk] = o1 - o0;                 // length; scanned in place below
    }
    if (tid < BKT) {
        int node = b * BKT + tid;
        nrmL[tid] = (node < n) ? norm[node] : 1.0f;
    }
    if (tid == 0) carry = 0;
    __syncthreads();
    // in-place exclusive scan of dstoff[0..NBLK)
    for (int bp = 0; bp < NBLK; bp += GTHREADS) {
        int idx = bp + tid;
        unsigned int orig = (idx < NBLK) ? dstoff[idx] : 0u;
        unsigned int v = orig;
        #pragma unroll
        for (int off = 1; off < 64; off <<= 1) {
            unsigned int t = __shfl_up(v, off);
            if (lane >= off) v += t;
        }
        if (lane == 63) wsums[wid] = v;
        __syncthreads();
        unsigned int add = carry;
        for (int w = 0; w < wid; ++w) add += wsums[w];
        if (idx < NBLK) dstoff[idx] = v - orig + add;
        __syncthreads();
        if (tid == 0) {
            unsigned int s = carry;
            for (int w = 0; w < GTHREADS / 64; ++w) s += wsums[w];
            carry = s;
        }
        __syncthreads();
    }
    if (tid == 0) dstoff[NBLK] = carry;
    __syncthreads();
    const int cnt = (int)dstoff[NBLK];
    const int nch = (cnt > CAPB) ? (cnt + CAPB - 1) / CAPB : 1;

    const int fl  = lane & 7;                  // uint4 index within 128B row
    const int oct = lane >> 3;                 // node within 8-node group

    for (int c = 0; c < nch; ++c) {
        const unsigned int lo = (unsigned int)c * CAPB;
        const unsigned int hi = min((unsigned int)cnt, lo + (unsigned int)CAPB);
        const int wlen = (int)(hi - lo);
        // copy window [lo,hi) into recs (recs not read by previous chunk's gather)
        for (int blk = wid; blk < NBLK; blk += GTHREADS / 64) {
            unsigned int dbase = dstoff[blk], dend = dstoff[blk + 1];
            unsigned int s0 = max(dbase, lo), s1 = min(dend, hi);
            if (s0 < s1) {
                size_t glo = (size_t)blk * EPB + segoff[blk] + (s0 - dbase);
                for (unsigned int j = lane; j < s1 - s0; j += 64)
                    recs[s0 - lo + j] = recB[glo + j];
            }
        }
        __syncthreads();                        // prev gather done + copy done
        if (tid < BKT) hist[tid] = 0;
        __syncthreads();
        for (int i = tid; i < wlen; i += GTHREADS) atomicAdd(&hist[recs[i] & (BKT - 1)], 1);
        __syncthreads();
        // scan hist[0..BKT) (threads < 256 = 4 waves)
        {
            int v = (tid < BKT) ? hist[tid] : 0;
            #pragma unroll
            for (int off = 1; off < 64; off <<= 1) {
                int t = __shfl_up(v, off);
                if (lane >= off) v += t;
            }
            if (tid < BKT && lane == 63) wsums[wid] = (unsigned int)v;
            __syncthreads();
            if (tid < BKT) {
                int add = 0;
                for (int w = 0; w < wid; ++w) add += (int)wsums[w];
                int excl = v + add - hist[tid];
                rankb[tid] = excl;
                rsL[tid]   = excl;
            }
        }
        __syncthreads();
        for (int i = tid; i < wlen; i += GTHREADS) {
            unsigned int v = recs[i];
            int pos = atomicAdd(&rankb[v & (BKT - 1)], 1);
            srcs[pos] = (int)(v >> 8);
        }
        __syncthreads();

        // ---- gather ----
        #pragma unroll
        for (int r = 0; r < BKT / 128; ++r) {  // 2 rounds of 128 nodes
            int ln   = r * 128 + wid * 8 + oct;
            int node = b * BKT + ln;
            bool valid = node < n;
            int rsl = valid ? rsL[ln]  : 0;
            int cl  = valid ? hist[ln] : 0;
            int m = cl;                        // uniform loop count = wave-max
            m = max(m, __shfl_xor(m, 8));
            m = max(m, __shfl_xor(m, 16));
            m = max(m, __shfl_xor(m, 32));
            float a0 = 0.f, a1 = 0.f, a2 = 0.f, a3 = 0.f;
            float a4 = 0.f, a5 = 0.f, a6 = 0.f, a7 = 0.f;
            for (int k = 0; k < m; k += 8) {
                int sb[8];
                #pragma unroll
                for (int j = 0; j < 8; ++j) {  // 8 LDS reads issue together
                    int kj = k + j;
                    sb[j] = (kj < cl) ? (int)srcs[rsl + kj] : -1;
                }
                #pragma unroll
                for (int j = 0; j < 8; ++j) {  // 8 row loads in flight
                    bool take = sb[j] >= 0;
                    int s = take ? sb[j] : 0;  // dummy hits node 0's cached row
                    uint4 v = yr4[(size_t)s * 8 + fl];
                    if (!take) { v.x = 0u; v.y = 0u; v.z = 0u; v.w = 0u; }
                    a0 += bf2f_lo(v.x); a1 += bf2f_hi(v.x);
                    a2 += bf2f_lo(v.y); a3 += bf2f_hi(v.y);
                    a4 += bf2f_lo(v.z); a5 += bf2f_hi(v.z);
                    a6 += bf2f_lo(v.w); a7 += bf2f_hi(v.w);
                }
            }
            if (valid) {
                float nt = nrmL[ln];
                size_t basei = (size_t)node * 16 + fl * 2;
                float4 r0, r1;
                if (c == 0) {
                    float4 xv0 = x4[basei], xv1 = x4[basei + 1];
                    r0.x = a0 * nt + EPS * xv0.x;  r0.y = a1 * nt + EPS * xv0.y;
                    r0.z = a2 * nt + EPS * xv0.z;  r0.w = a3 * nt + EPS * xv0.w;
                    r1.x = a4 * nt + EPS * xv1.x;  r1.y = a5 * nt + EPS * xv1.y;
                    r1.z = a6 * nt + EPS * xv1.z;  r1.w = a7 * nt + EPS * xv1.w;
                } else {                       // rare multi-chunk path: RMW
                    float4 p0 = out4[basei], p1 = out4[basei + 1];
                    r0.x = p0.x + a0 * nt;  r0.y = p0.y + a1 * nt;
                    r0.z = p0.z + a2 * nt;  r0.w = p0.w + a3 * nt;
                    r1.x = p1.x + a4 * nt;  r1.y = p1.y + a5 * nt;
                    r1.z = p1.z + a6 * nt;  r1.w = p1.w + a7 * nt;
                }
                out4[basei] = r0;              // coalesced: 32B/lane
                out4[basei + 1] = r1;
            }
        }
    }
}

// ---------------- tiny-ws / big-n fallback (round-1 proven) ----------------

__global__ void fb_hist(const int* __restrict__ src, int* __restrict__ deg, int E) {
    int e = blockIdx.x * blockDim.x + threadIdx.x;
    if (e < E) atomicAdd(&deg[src[e]], 1);
}
__global__ void fb_norm(const int* __restrict__ deg, float* __restrict__ norm, int n) {
    int i = blockIdx.x * blockDim.x + threadIdx.x;
    if (i < n) norm[i] = rsqrtf(fmaxf((float)deg[i], 1.0f));
}
__global__ void fb_init_out(const float4* __restrict__ x, float4* __restrict__ out, int n4) {
    int i = blockIdx.x * blockDim.x + threadIdx.x;
    if (i < n4) {
        float4 v = x[i];
        out[i] = make_float4(v.x * EPS, v.y * EPS, v.z * EPS, v.w * EPS);
    }
}
__global__ void fb_scatter(const float* __restrict__ x, const int* __restrict__ src,
                           const int* __restrict__ dst, const float* __restrict__ norm,
                           float* __restrict__ out, int E) {
    long long tid = (long long)blockIdx.x * blockDim.x + threadIdx.x;
    int e = (int)(tid >> 6), d = (int)(tid & 63);
    if (e < E) {
        int s = src[e], t = dst[e];
        atomicAdd(&out[(size_t)t * D + d], norm[s] * norm[t] * x[(size_t)s * D + d]);
    }
}

// ---------------- launcher ----------------

extern "C" void kernel_launch(void* const* d_in, const int* in_sizes, int n_in,
                              void* d_out, int out_size, void* d_ws, size_t ws_size,
                              hipStream_t stream) {
    const float* x   = (const float*)d_in[0];
    const int*   src = (const int*)d_in[1];
    const int*   dst = (const int*)d_in[2];
    float* out = (float*)d_out;

    const int ND = in_sizes[0];
    const int E  = in_sizes[1];
    const int n  = ND / D;
    const int NB   = (n + BKT - 1) / BKT;
    const int NBLK = (E + EPB - 1) / EPB;
    const int NBP  = NB + 1;
    constexpr int B = 256;

    // workspace layout (16B-aligned chunks)
    size_t off = 0;
    auto take = [&](size_t bytes) { size_t o = off; off = (off + bytes + 15) & ~15ull; return o; };
    size_t o_rec  = take((size_t)NBLK * EPB * 4);       // recB u32
    size_t o_srec = take((size_t)NBLK * EPB);           // srecB u8
    size_t o_tabD = take((size_t)NBLK * NBP * 2);       // tabD u16
    size_t o_tabS = take((size_t)NBLK * NBP * 2);       // tabS u16
    size_t o_yh   = take((size_t)ND * 2);               // yh u32 (bf16x2)
    size_t o_norm = take((size_t)n * 4);                // norm f32
    size_t need = off;

    if (NB <= NBMAX && NBLK <= MAXBLK && n < (1 << 24) && need <= ws_size && E > 0) {
        char* ws = (char*)d_ws;
        unsigned int*   recB  = (unsigned int*)(ws + o_rec);
        unsigned char*  srecB = (unsigned char*)(ws + o_srec);
        unsigned short* tabD  = (unsigned short*)(ws + o_tabD);
        unsigned short* tabS  = (unsigned short*)(ws + o_tabS);
        unsigned int*   yh    = (unsigned int*)(ws + o_yh);
        float*          norm  = (float*)(ws + o_norm);

        partition_kernel<<<NBLK, PTHREADS, 0, stream>>>(src, dst, recB, srecB,
                                                        tabD, tabS, E, NB, NBP);
        normyh_kernel<<<NB, B, 0, stream>>>(srecB, tabS, (const float2*)x, yh, norm,
                                            n, NBLK, NBP);
        sortgather_kernel<<<NB, GTHREADS, 0, stream>>>(recB, tabD, norm, (const uint4*)yh,
                                                       (const float4*)x, (float4*)out,
                                                       n, NBLK, NBP);
    } else {
        int*   deg  = (int*)d_ws;
        float* norm = (float*)d_ws + n;
        hipMemsetAsync(deg, 0, (size_t)n * sizeof(int), stream);
        fb_hist<<<(E + B - 1) / B, B, 0, stream>>>(src, deg, E);
        fb_norm<<<(n + B - 1) / B, B, 0, stream>>>(deg, norm, n);
        fb_init_out<<<(ND / 4 + B - 1) / B, B, 0, stream>>>((const float4*)x, (float4*)out, ND / 4);
        long long total = (long long)E * D;
        fb_scatter<<<(int)((total + B - 1) / B), B, 0, stream>>>(x, src, dst, norm, out, E);
    }
}

// Round 6
// 166.485 us; speedup vs baseline: 1.0789x; 1.0789x over previous
//
#include <hip/hip_runtime.h>

// GCN aggregation: out[t] = norm[t] * sum_{e:dst=t} norm[src]*x[src] + EPS*x[t]
// Round 15: sortgather occupancy fix. Round 14's sortgather ran at 84 us
// (vs 45 us for the round-9 LDS-free gather): 1024 thr = 16 waves hits the
// 32-wave/CU cap at 2 blocks AND 59.9 KB LDS caps at 2 blocks -> 32% occupancy,
// 2.0 TB/s on the same 138 MB fetch. The gather is latency-bound scattered
// 128B row reads -> wants waves, not LDS. Now: 512 threads (8 waves), CAPB
// 4096, MAXBLK 512 -> ~39 KB LDS -> 4 blocks/CU = 32 waves/CU. Segment copy
// and normyh histogram reads use 16-lane groups (coalesced, balanced) instead
// of one segment per 64-lane wave. Partition (per-block-region streaming,
// no global atomics) unchanged. 3 launches.
constexpr int D        = 64;
constexpr float EPS    = 0.5f;
constexpr int BKT      = 256;    // nodes per bucket
constexpr int CAPB     = 4096;   // sortgather LDS chunk capacity (records)
constexpr int EPB      = 4096;   // edges per partition block (= region stride)
constexpr int PTHREADS = 512;
constexpr int EPT      = EPB / PTHREADS;   // 8
constexpr int GTHREADS = 512;    // sortgather block size (8 waves)
constexpr int NBMAX    = 1024;   // max node buckets
constexpr int MAXBLK   = 512;    // max partition blocks (E <= MAXBLK*EPB)

__device__ __forceinline__ unsigned int f2bf(float f) {
    unsigned int u = __float_as_uint(f);
    return (u + 0x7FFFu + ((u >> 16) & 1u)) >> 16;   // RNE to bf16
}
__device__ __forceinline__ float bf2f_lo(unsigned int v) { return __uint_as_float(v << 16); }
__device__ __forceinline__ float bf2f_hi(unsigned int v) { return __uint_as_float(v & 0xFFFF0000u); }

// ---------------- main path ----------------

// Each block owns edges [blk*EPB, blk*EPB+cnt) and its own output region.
// Writes: recB[blk][i] (u32, sorted by dst-bucket), srecB[blk][i] (u8, sorted
// by src-bucket), tabD/tabS[blk][0..NB] = exclusive scan (u16). All streaming.
__global__ __launch_bounds__(PTHREADS)
void partition_kernel(const int* __restrict__ src, const int* __restrict__ dst,
                      unsigned int* __restrict__ recB, unsigned char* __restrict__ srecB,
                      unsigned short* __restrict__ tabD, unsigned short* __restrict__ tabS,
                      int E, int NB, int NBP) {
    __shared__ unsigned int  srt[EPB];      // 16 KB sorted dst-records
    __shared__ unsigned char ssrt[EPB];     // 4 KB sorted src bytes
    __shared__ int histD[NBMAX];            // count, then rank
    __shared__ int histS[NBMAX];
    __shared__ unsigned int rsD[NBMAX];     // exclusive scan
    __shared__ unsigned int rsS[NBMAX];
    __shared__ unsigned int wsums[PTHREADS / 64];
    __shared__ unsigned int carry;

    const int blk  = blockIdx.x;
    const int base = blk * EPB;
    const int tid  = threadIdx.x;
    const int lane = tid & 63;
    const int wid  = tid >> 6;
    const int cnt  = min(EPB, E - base);
    const bool full = (cnt == EPB);

    for (int b = tid; b < NB; b += PTHREADS) { histD[b] = 0; histS[b] = 0; }
    __syncthreads();

    // ---- pass 1: count per bucket ----
    if (full) {
        const int4* s4 = (const int4*)(src + base);
        const int4* d4 = (const int4*)(dst + base);
        #pragma unroll
        for (int k = 0; k < EPT / 4; ++k) {
            int4 sv = s4[tid + k * PTHREADS];
            int4 dv = d4[tid + k * PTHREADS];
            atomicAdd(&histD[dv.x >> 8], 1); atomicAdd(&histS[sv.x >> 8], 1);
            atomicAdd(&histD[dv.y >> 8], 1); atomicAdd(&histS[sv.y >> 8], 1);
            atomicAdd(&histD[dv.z >> 8], 1); atomicAdd(&histS[sv.z >> 8], 1);
            atomicAdd(&histD[dv.w >> 8], 1); atomicAdd(&histS[sv.w >> 8], 1);
        }
    } else {
        for (int k = 0; k < EPT; ++k) {
            int e = tid + k * PTHREADS;
            if (e < cnt) {
                atomicAdd(&histD[dst[base + e] >> 8], 1);
                atomicAdd(&histS[src[base + e] >> 8], 1);
            }
        }
    }
    __syncthreads();

    // ---- exclusive scan histD->rsD (zeroing histD for rank reuse) ----
    if (tid == 0) carry = 0;
    __syncthreads();
    for (int bp = 0; bp < NB; bp += PTHREADS) {
        int idx = bp + tid;
        unsigned int orig = (idx < NB) ? (unsigned int)histD[idx] : 0u;
        if (idx < NB) histD[idx] = 0;
        unsigned int v = orig;
        #pragma unroll
        for (int off = 1; off < 64; off <<= 1) {
            unsigned int t = __shfl_up(v, off);
            if (lane >= off) v += t;
        }
        if (lane == 63) wsums[wid] = v;
        __syncthreads();
        unsigned int add = carry;
        for (int w = 0; w < wid; ++w) add += wsums[w];
        if (idx < NB) rsD[idx] = v - orig + add;
        __syncthreads();
        if (tid == 0) {
            unsigned int s = carry;
            for (int w = 0; w < PTHREADS / 64; ++w) s += wsums[w];
            carry = s;
        }
        __syncthreads();
    }
    // ---- exclusive scan histS->rsS ----
    if (tid == 0) carry = 0;
    __syncthreads();
    for (int bp = 0; bp < NB; bp += PTHREADS) {
        int idx = bp + tid;
        unsigned int orig = (idx < NB) ? (unsigned int)histS[idx] : 0u;
        if (idx < NB) histS[idx] = 0;
        unsigned int v = orig;
        #pragma unroll
        for (int off = 1; off < 64; off <<= 1) {
            unsigned int t = __shfl_up(v, off);
            if (lane >= off) v += t;
        }
        if (lane == 63) wsums[wid] = v;
        __syncthreads();
        unsigned int add = carry;
        for (int w = 0; w < wid; ++w) add += wsums[w];
        if (idx < NB) rsS[idx] = v - orig + add;
        __syncthreads();
        if (tid == 0) {
            unsigned int s = carry;
            for (int w = 0; w < PTHREADS / 64; ++w) s += wsums[w];
            carry = s;
        }
        __syncthreads();
    }

    // ---- write prefix tables (coalesced u16) ----
    for (int b = tid; b <= NB; b += PTHREADS) {
        unsigned short vD = (unsigned short)((b < NB) ? rsD[b] : (unsigned int)cnt);
        unsigned short vS = (unsigned short)((b < NB) ? rsS[b] : (unsigned int)cnt);
        tabD[(size_t)blk * NBP + b] = vD;
        tabS[(size_t)blk * NBP + b] = vS;
    }

    // ---- pass 2: place into LDS sorted position ----
    if (full) {
        const int4* s4 = (const int4*)(src + base);
        const int4* d4 = (const int4*)(dst + base);
        #pragma unroll
        for (int k = 0; k < EPT / 4; ++k) {
            int4 sv = s4[tid + k * PTHREADS];
            int4 dv = d4[tid + k * PTHREADS];
            int ss[4] = {sv.x, sv.y, sv.z, sv.w};
            int tt[4] = {dv.x, dv.y, dv.z, dv.w};
            #pragma unroll
            for (int j = 0; j < 4; ++j) {
                int s = ss[j], t = tt[j];
                int bD = t >> 8;
                int r  = atomicAdd(&histD[bD], 1);
                srt[rsD[bD] + r] = ((unsigned int)s << 8) | (unsigned int)(t & (BKT - 1));
                int bS = s >> 8;
                int r2 = atomicAdd(&histS[bS], 1);
                ssrt[rsS[bS] + r2] = (unsigned char)(s & (BKT - 1));
            }
        }
    } else {
        for (int k = 0; k < EPT; ++k) {
            int e = tid + k * PTHREADS;
            if (e < cnt) {
                int s = src[base + e], t = dst[base + e];
                int bD = t >> 8;
                int r  = atomicAdd(&histD[bD], 1);
                srt[rsD[bD] + r] = ((unsigned int)s << 8) | (unsigned int)(t & (BKT - 1));
                int bS = s >> 8;
                int r2 = atomicAdd(&histS[bS], 1);
                ssrt[rsS[bS] + r2] = (unsigned char)(s & (BKT - 1));
            }
        }
    }
    __syncthreads();

    // ---- pass 3: stream full region out (bytes beyond cnt are never read) ----
    {
        uint4* go = (uint4*)(recB + (size_t)blk * EPB);
        const uint4* gi = (const uint4*)srt;
        for (int i = tid; i < EPB / 4; i += PTHREADS) go[i] = gi[i];
        uint4* so = (uint4*)(srecB + (size_t)blk * EPB);
        const uint4* si = (const uint4*)ssrt;
        for (int i = tid; i < EPB / 16; i += PTHREADS) so[i] = si[i];
    }
}

// Per-bucket: out-degree histogram from srecB segments -> norm[] -> yh.
// Segments read by 16-lane groups (coalesced consecutive bytes, balanced).
__global__ __launch_bounds__(256)
void normyh_kernel(const unsigned char* __restrict__ srecB, const unsigned short* __restrict__ tabS,
                   const float2* __restrict__ x2, unsigned int* __restrict__ yh,
                   float* __restrict__ norm, int n, int NBLK, int NBP) {
    const int b   = blockIdx.x;
    const int tid = threadIdx.x;
    __shared__ int hist[BKT];
    __shared__ float nrm[BKT];
    hist[tid] = 0;                             // BKT == blockDim == 256
    __syncthreads();
    const int g  = tid >> 4;                   // 16 groups of 16 lanes
    const int gl = tid & 15;
    for (int blk = g; blk < NBLK; blk += 16) {
        int o0 = tabS[(size_t)blk * NBP + b];
        int o1 = tabS[(size_t)blk * NBP + b + 1];
        const unsigned char* p = srecB + (size_t)blk * EPB;
        for (int j = o0 + gl; j < o1; j += 16) atomicAdd(&hist[p[j]], 1);
    }
    __syncthreads();
    int node = b * BKT + tid;
    float nm = rsqrtf(fmaxf((float)hist[tid], 1.0f));
    nrm[tid] = nm;
    if (node < n) norm[node] = nm;
    __syncthreads();
    int nodes = n - b * BKT;
    if (nodes > BKT) nodes = BKT;
    if (nodes < 0) nodes = 0;
    int total = nodes * (D / 2);               // float2 elements in this bucket
    size_t gbase = (size_t)b * BKT * (D / 2);
    for (int i = tid; i < total; i += 256) {   // contiguous -> coalesced
        float2 v = x2[gbase + i];
        float nm2 = nrm[i >> 5];
        yh[gbase + i] = f2bf(v.x * nm2) | (f2bf(v.y * nm2) << 16);
    }
}

// One block per bucket (512 threads = 8 waves, ~39 KB LDS -> 4 blocks/CU =
// 32 waves/CU). Gather bucket b's records from per-block segments into LDS
// (16-lane groups), counting-sort to per-node src lists, then gather yh rows
// (8 nodes/wave, 8-deep unroll). Chunked if cnt > CAPB (rare).
__global__ __launch_bounds__(GTHREADS)
void sortgather_kernel(const unsigned int* __restrict__ recB, const unsigned short* __restrict__ tabD,
                       const float* __restrict__ norm, const uint4* __restrict__ yr4,
                       const float4* __restrict__ x4, float4* __restrict__ out4,
                       int n, int NBLK, int NBP) {
    __shared__ unsigned int recs[CAPB];        // 16 KB
    __shared__ unsigned int srcs[CAPB];        // 16 KB
    __shared__ unsigned short segoff[MAXBLK];  // 1 KB
    __shared__ unsigned int dstoff[MAXBLK + 1];// 2 KB (len -> exclusive scan)
    __shared__ int hist[BKT];                  // 1 KB
    __shared__ int rankb[BKT];                 // 1 KB
    __shared__ int rsL[BKT];                   // 1 KB
    __shared__ float nrmL[BKT];                // 1 KB
    __shared__ unsigned int wsums[GTHREADS / 64];
    __shared__ unsigned int carry;
    const int b    = blockIdx.x;
    const int tid  = threadIdx.x;
    const int lane = tid & 63;
    const int wid  = tid >> 6;

    // segment table for this bucket
    for (int blk = tid; blk < NBLK; blk += GTHREADS) {
        unsigned int o0 = tabD[(size_t)blk * NBP + b];
        unsigned int o1 = tabD[(size_t)blk * NBP + b + 1];
        segoff[blk] = (unsigned short)o0;
        dstoff[blk] = o1 - o0;                 // length; scanned in place below
    }
    if (tid < BKT) {
        int node = b * BKT + tid;
        nrmL[tid] = (node < n) ? norm[node] : 1.0f;
    }
    if (tid == 0) carry = 0;
    __syncthreads();
    // in-place exclusive scan of dstoff[0..NBLK)
    for (int bp = 0; bp < NBLK; bp += GTHREADS) {
        int idx = bp + tid;
        unsigned int orig = (idx < NBLK) ? dstoff[idx] : 0u;
        unsigned int v = orig;
        #pragma unroll
        for (int off = 1; off < 64; off <<= 1) {
            unsigned int t = __shfl_up(v, off);
            if (lane >= off) v += t;
        }
        if (lane == 63) wsums[wid] = v;
        __syncthreads();
        unsigned int add = carry;
        for (int w = 0; w < wid; ++w) add += wsums[w];
        if (idx < NBLK) dstoff[idx] = v - orig + add;
        __syncthreads();
        if (tid == 0) {
            unsigned int s = carry;
            for (int w = 0; w < GTHREADS / 64; ++w) s += wsums[w];
            carry = s;
        }
        __syncthreads();
    }
    if (tid == 0) dstoff[NBLK] = carry;
    __syncthreads();
    const int cnt = (int)dstoff[NBLK];
    const int nch = (cnt > CAPB) ? (cnt + CAPB - 1) / CAPB : 1;

    const int fl  = lane & 7;                  // uint4 index within 128B row
    const int oct = lane >> 3;                 // node within 8-node group

    for (int c = 0; c < nch; ++c) {
        const unsigned int lo = (unsigned int)c * CAPB;
        const unsigned int hi = min((unsigned int)cnt, lo + (unsigned int)CAPB);
        const int wlen = (int)(hi - lo);
        // copy window [lo,hi) into recs; 16-lane groups per segment (avg ~10
        // records/segment -> coalesced ~40B reads, balanced across 32 groups)
        {
            const int g  = tid >> 4;
            const int gl = tid & 15;
            for (int blk = g; blk < NBLK; blk += GTHREADS / 16) {
                unsigned int dbase = dstoff[blk], dend = dstoff[blk + 1];
                unsigned int s0 = max(dbase, lo), s1 = min(dend, hi);
                if (s0 < s1) {
                    size_t glo = (size_t)blk * EPB + segoff[blk] + (s0 - dbase);
                    for (unsigned int j = gl; j < s1 - s0; j += 16)
                        recs[s0 - lo + j] = recB[glo + j];
                }
            }
        }
        __syncthreads();                        // prev gather done + copy done
        if (tid < BKT) hist[tid] = 0;
        __syncthreads();
        for (int i = tid; i < wlen; i += GTHREADS) atomicAdd(&hist[recs[i] & (BKT - 1)], 1);
        __syncthreads();
        // scan hist[0..BKT) (threads < 256 = 4 waves)
        {
            int v = (tid < BKT) ? hist[tid] : 0;
            #pragma unroll
            for (int off = 1; off < 64; off <<= 1) {
                int t = __shfl_up(v, off);
                if (lane >= off) v += t;
            }
            if (tid < BKT && lane == 63) wsums[wid] = (unsigned int)v;
            __syncthreads();
            if (tid < BKT) {
                int add = 0;
                for (int w = 0; w < wid; ++w) add += (int)wsums[w];
                int excl = v + add - hist[tid];
                rankb[tid] = excl;
                rsL[tid]   = excl;
            }
        }
        __syncthreads();
        for (int i = tid; i < wlen; i += GTHREADS) {
            unsigned int v = recs[i];
            int pos = atomicAdd(&rankb[v & (BKT - 1)], 1);
            srcs[pos] = v >> 8;
        }
        __syncthreads();

        // ---- gather: 8 waves x 8 nodes -> 64 nodes/round, 4 rounds ----
        #pragma unroll
        for (int r = 0; r < BKT / 64; ++r) {
            int ln   = r * 64 + wid * 8 + oct;
            int node = b * BKT + ln;
            bool valid = node < n;
            int rsl = valid ? rsL[ln]  : 0;
            int cl  = valid ? hist[ln] : 0;
            int m = cl;                        // uniform loop count = wave-max
            m = max(m, __shfl_xor(m, 8));
            m = max(m, __shfl_xor(m, 16));
            m = max(m, __shfl_xor(m, 32));
            float a0 = 0.f, a1 = 0.f, a2 = 0.f, a3 = 0.f;
            float a4 = 0.f, a5 = 0.f, a6 = 0.f, a7 = 0.f;
            for (int k = 0; k < m; k += 8) {
                int sb[8];
                #pragma unroll
                for (int j = 0; j < 8; ++j) {  // 8 LDS reads issue together
                    int kj = k + j;
                    sb[j] = (kj < cl) ? (int)srcs[rsl + kj] : -1;
                }
                #pragma unroll
                for (int j = 0; j < 8; ++j) {  // 8 row loads in flight
                    bool take = sb[j] >= 0;
                    int s = take ? sb[j] : 0;  // dummy hits node 0's cached row
                    uint4 v = yr4[(size_t)s * 8 + fl];
                    if (!take) { v.x = 0u; v.y = 0u; v.z = 0u; v.w = 0u; }
                    a0 += bf2f_lo(v.x); a1 += bf2f_hi(v.x);
                    a2 += bf2f_lo(v.y); a3 += bf2f_hi(v.y);
                    a4 += bf2f_lo(v.z); a5 += bf2f_hi(v.z);
                    a6 += bf2f_lo(v.w); a7 += bf2f_hi(v.w);
                }
            }
            if (valid) {
                float nt = nrmL[ln];
                size_t basei = (size_t)node * 16 + fl * 2;
                float4 r0, r1;
                if (c == 0) {
                    float4 xv0 = x4[basei], xv1 = x4[basei + 1];
                    r0.x = a0 * nt + EPS * xv0.x;  r0.y = a1 * nt + EPS * xv0.y;
                    r0.z = a2 * nt + EPS * xv0.z;  r0.w = a3 * nt + EPS * xv0.w;
                    r1.x = a4 * nt + EPS * xv1.x;  r1.y = a5 * nt + EPS * xv1.y;
                    r1.z = a6 * nt + EPS * xv1.z;  r1.w = a7 * nt + EPS * xv1.w;
                } else {                       // rare multi-chunk path: RMW
                    float4 p0 = out4[basei], p1 = out4[basei + 1];
                    r0.x = p0.x + a0 * nt;  r0.y = p0.y + a1 * nt;
                    r0.z = p0.z + a2 * nt;  r0.w = p0.w + a3 * nt;
                    r1.x = p1.x + a4 * nt;  r1.y = p1.y + a5 * nt;
                    r1.z = p1.z + a6 * nt;  r1.w = p1.w + a7 * nt;
                }
                out4[basei] = r0;              // coalesced: 32B/lane
                out4[basei + 1] = r1;
            }
        }
    }
}

// ---------------- tiny-ws / big-n fallback (round-1 proven) ----------------

__global__ void fb_hist(const int* __restrict__ src, int* __restrict__ deg, int E) {
    int e = blockIdx.x * blockDim.x + threadIdx.x;
    if (e < E) atomicAdd(&deg[src[e]], 1);
}
__global__ void fb_norm(const int* __restrict__ deg, float* __restrict__ norm, int n) {
    int i = blockIdx.x * blockDim.x + threadIdx.x;
    if (i < n) norm[i] = rsqrtf(fmaxf((float)deg[i], 1.0f));
}
__global__ void fb_init_out(const float4* __restrict__ x, float4* __restrict__ out, int n4) {
    int i = blockIdx.x * blockDim.x + threadIdx.x;
    if (i < n4) {
        float4 v = x[i];
        out[i] = make_float4(v.x * EPS, v.y * EPS, v.z * EPS, v.w * EPS);
    }
}
__global__ void fb_scatter(const float* __restrict__ x, const int* __restrict__ src,
                           const int* __restrict__ dst, const float* __restrict__ norm,
                           float* __restrict__ out, int E) {
    long long tid = (long long)blockIdx.x * blockDim.x + threadIdx.x;
    int e = (int)(tid >> 6), d = (int)(tid & 63);
    if (e < E) {
        int s = src[e], t = dst[e];
        atomicAdd(&out[(size_t)t * D + d], norm[s] * norm[t] * x[(size_t)s * D + d]);
    }
}

// ---------------- launcher ----------------

extern "C" void kernel_launch(void* const* d_in, const int* in_sizes, int n_in,
                              void* d_out, int out_size, void* d_ws, size_t ws_size,
                              hipStream_t stream) {
    const float* x   = (const float*)d_in[0];
    const int*   src = (const int*)d_in[1];
    const int*   dst = (const int*)d_in[2];
    float* out = (float*)d_out;

    const int ND = in_sizes[0];
    const int E  = in_sizes[1];
    const int n  = ND / D;
    const int NB   = (n + BKT - 1) / BKT;
    const int NBLK = (E + EPB - 1) / EPB;
    const int NBP  = NB + 1;
    constexpr int B = 256;

    // workspace layout (16B-aligned chunks)
    size_t off = 0;
    auto take = [&](size_t bytes) { size_t o = off; off = (off + bytes + 15) & ~15ull; return o; };
    size_t o_rec  = take((size_t)NBLK * EPB * 4);       // recB u32
    size_t o_srec = take((size_t)NBLK * EPB);           // srecB u8
    size_t o_tabD = take((size_t)NBLK * NBP * 2);       // tabD u16
    size_t o_tabS = take((size_t)NBLK * NBP * 2);       // tabS u16
    size_t o_yh   = take((size_t)ND * 2);               // yh u32 (bf16x2)
    size_t o_norm = take((size_t)n * 4);                // norm f32
    size_t need = off;

    if (NB <= NBMAX && NBLK <= MAXBLK && n < (1 << 24) && need <= ws_size && E > 0) {
        char* ws = (char*)d_ws;
        unsigned int*   recB  = (unsigned int*)(ws + o_rec);
        unsigned char*  srecB = (unsigned char*)(ws + o_srec);
        unsigned short* tabD  = (unsigned short*)(ws + o_tabD);
        unsigned short* tabS  = (unsigned short*)(ws + o_tabS);
        unsigned int*   yh    = (unsigned int*)(ws + o_yh);
        float*          norm  = (float*)(ws + o_norm);

        partition_kernel<<<NBLK, PTHREADS, 0, stream>>>(src, dst, recB, srecB,
                                                        tabD, tabS, E, NB, NBP);
        normyh_kernel<<<NB, B, 0, stream>>>(srecB, tabS, (const float2*)x, yh, norm,
                                            n, NBLK, NBP);
        sortgather_kernel<<<NB, GTHREADS, 0, stream>>>(recB, tabD, norm, (const uint4*)yh,
                                                       (const float4*)x, (float4*)out,
                                                       n, NBLK, NBP);
    } else {
        int*   deg  = (int*)d_ws;
        float* norm = (float*)d_ws + n;
        hipMemsetAsync(deg, 0, (size_t)n * sizeof(int), stream);
        fb_hist<<<(E + B - 1) / B, B, 0, stream>>>(src, deg, E);
        fb_norm<<<(n + B - 1) / B, B, 0, stream>>>(deg, norm, n);
        fb_init_out<<<(ND / 4 + B - 1) / B, B, 0, stream>>>((const float4*)x, (float4*)out, ND / 4);
        long long total = (long long)E * D;
        fb_scatter<<<(int)((total + B - 1) / B), B, 0, stream>>>(x, src, dst, norm, out, E);
    }
}